// Round 4
// baseline (360.169 us; speedup 1.0000x reference)
//
#include <hip/hip_runtime.h>

// FIR 4x4 separable depthwise filter, k1=[1,3,3,1], k2=outer(k1,k1)/64.
// Input x: (8, 64, 512, 512) f32 -> 512 planes of 512x512.
// lax SAME padding: pad_lo=1, pad_hi=2 (zeros).
// out[r][c] = (1/64) * (H[r-1][c] + 3*H[r][c] + 3*H[r+1][c] + H[r+2][c])
//   H[y][c] = x[y][c-1] + 3*x[y][c] + 3*x[y][c+1] + x[y][c+2]
//
// One wave64 spans a full 512-wide row (8 floats/lane, 2x dwordx4).
// Column halo via lane shuffles (image edge == wave edge, uniform select).
// 2 rows per iteration: 4 KB contiguous read clause + 4 KB contiguous
// write burst per wave-iteration (fewer R/W turnarounds at the MC).
// Nontemporal stores: output is never re-read; keep L2 for read halos.

#define FIR_W 512
#define FIR_H 512
#define FIR_ROWS 64   // rows per wave-strip

typedef float fvec4 __attribute__((ext_vector_type(4)));  // native vec for nt-store

struct F8 { float4 a, b; };

__device__ __forceinline__ void nt_store4(float* addr, float4 v) {
    fvec4 n = {v.x, v.y, v.z, v.w};
    __builtin_nontemporal_store(n, reinterpret_cast<fvec4*>(addr));
}

__device__ __forceinline__ void load_row(const float* __restrict__ p, int y, int lane,
                                         float4& lo, float4& hi) {
    if ((unsigned)y < FIR_H) {   // y is wave-uniform: non-divergent
        const float* row = p + (size_t)y * FIR_W + lane * 8;
        lo = *reinterpret_cast<const float4*>(row);
        hi = *reinterpret_cast<const float4*>(row + 4);
    } else {
        lo.x = lo.y = lo.z = lo.w = 0.0f;
        hi = lo;
    }
}

__device__ __forceinline__ F8 hfilter(float4 lo, float4 hi, int lane) {
    float xm1 = __shfl_up(hi.w, 1);    // col c-1
    float xp8 = __shfl_down(lo.x, 1);  // col c+8
    float xp9 = __shfl_down(lo.y, 1);  // col c+9
    if (lane == 0)  xm1 = 0.0f;
    if (lane == 63) { xp8 = 0.0f; xp9 = 0.0f; }
    F8 h;
    h.a.x = xm1  + 3.0f * (lo.x + lo.y) + lo.z;
    h.a.y = lo.x + 3.0f * (lo.y + lo.z) + lo.w;
    h.a.z = lo.y + 3.0f * (lo.z + lo.w) + hi.x;
    h.a.w = lo.z + 3.0f * (lo.w + hi.x) + hi.y;
    h.b.x = lo.w + 3.0f * (hi.x + hi.y) + hi.z;
    h.b.y = hi.x + 3.0f * (hi.y + hi.z) + hi.w;
    h.b.z = hi.y + 3.0f * (hi.z + hi.w) + xp8;
    h.b.w = hi.z + 3.0f * (hi.w + xp8)  + xp9;
    return h;
}

__device__ __forceinline__ float4 vcomb(float4 h0, float4 h1, float4 h2, float4 h3) {
    const float s = 1.0f / 64.0f;
    float4 o;
    o.x = (h0.x + h3.x + 3.0f * (h1.x + h2.x)) * s;
    o.y = (h0.y + h3.y + 3.0f * (h1.y + h2.y)) * s;
    o.z = (h0.z + h3.z + 3.0f * (h1.z + h2.z)) * s;
    o.w = (h0.w + h3.w + 3.0f * (h1.w + h2.w)) * s;
    return o;
}

__global__ __launch_bounds__(256) void FIRFilter_88579405512825_kernel(
        const float* __restrict__ x, float* __restrict__ out) {
    const int lane  = threadIdx.x;                               // 0..63: 8 cols each
    const int strip = blockIdx.x * blockDim.y + threadIdx.y;     // 64-row strip
    const int plane = blockIdx.y;                                // 0..511: (b, c) plane

    const float* p = x   + (size_t)plane * (FIR_W * FIR_H);
    float*       q = out + (size_t)plane * (FIR_W * FIR_H);

    const int r0 = strip * FIR_ROWS;

    // Window: hm1=H(r-1), h0=H(r), hp1=H(r+1) entering iteration r.
    F8 hm1, h0, hp1;
    {
        float4 lo, hi;
        load_row(p, r0 - 1, lane, lo, hi); hm1 = hfilter(lo, hi, lane);
        load_row(p, r0,     lane, lo, hi); h0  = hfilter(lo, hi, lane);
        load_row(p, r0 + 1, lane, lo, hi); hp1 = hfilter(lo, hi, lane);
    }

    #pragma unroll 2
    for (int r = r0; r < r0 + FIR_ROWS; r += 2) {
        // Batched 4 KB read clause: rows r+2, r+3 (contiguous in memory).
        float4 lo2, hi2, lo3, hi3;
        load_row(p, r + 2, lane, lo2, hi2);
        load_row(p, r + 3, lane, lo3, hi3);
        F8 hp2 = hfilter(lo2, hi2, lane);
        F8 hp3 = hfilter(lo3, hi3, lane);

        // out[r] and out[r+1]: 4 KB contiguous nontemporal write burst.
        float4 o0a = vcomb(hm1.a, h0.a, hp1.a, hp2.a);
        float4 o0b = vcomb(hm1.b, h0.b, hp1.b, hp2.b);
        float4 o1a = vcomb(h0.a, hp1.a, hp2.a, hp3.a);
        float4 o1b = vcomb(h0.b, hp1.b, hp2.b, hp3.b);

        float* qr = q + (size_t)r * FIR_W + lane * 8;
        nt_store4(qr,             o0a);
        nt_store4(qr + 4,         o0b);
        nt_store4(qr + FIR_W,     o1a);
        nt_store4(qr + FIR_W + 4, o1b);

        hm1 = hp1; h0 = hp2; hp1 = hp3;
    }
}

extern "C" void kernel_launch(void* const* d_in, const int* in_sizes, int n_in,
                              void* d_out, int out_size, void* d_ws, size_t ws_size,
                              hipStream_t stream) {
    const float* x = (const float*)d_in[0];
    float* out = (float*)d_out;

    const int planes = in_sizes[0] / (FIR_W * FIR_H);   // 8*64 = 512

    // block: 64 lanes (one wave per row-strip) x 4 strips = 256 threads
    dim3 block(64, 4);
    // grid.x: 512 rows / (64 rows * 4 strips) = 2 ; grid.y: planes
    dim3 grid(FIR_H / (FIR_ROWS * 4), planes);

    FIRFilter_88579405512825_kernel<<<grid, block, 0, stream>>>(x, out);
}

// Round 5
// 327.351 us; speedup vs baseline: 1.1003x; 1.1003x over previous
//
#include <hip/hip_runtime.h>

// FIR 4x4 separable depthwise filter, k1=[1,3,3,1], k2=outer(k1,k1)/64.
// Input x: (8, 64, 512, 512) f32 -> 512 planes of 512x512.
// lax SAME padding: pad_lo=1, pad_hi=2 (zeros).
// out[r][c] = (1/64) * (H[r-1][c] + 3*H[r][c] + 3*H[r+1][c] + H[r+2][c])
//   H[y][c] = x[y][c-1] + 3*x[y][c] + 3*x[y][c+1] + x[y][c+2]
//
// One wave64 spans a full 512-wide row (8 floats/lane, 2x dwordx4).
// Column halo via lane shuffles (image edge == wave edge, uniform select).
// Explicit 2-stage software pipeline: rows for iteration k+1 are loaded into
// rotating register buffers (A/B, statically indexed via manual 2x unroll)
// while iteration k computes+stores -- keeps 4 loads in flight across the
// consume point instead of draining vmcnt every 2 rows.
// Plain stores (R4 lesson: nontemporal stores doubled WRITE_SIZE via
// partial-line RMW at the MC).

#define FIR_W 512
#define FIR_H 512
#define FIR_ROWS 64   // rows per wave-strip

struct F8 { float4 a, b; };

__device__ __forceinline__ void load_row(const float* __restrict__ p, int y, int lane,
                                         float4& lo, float4& hi) {
    if ((unsigned)y < FIR_H) {   // y is wave-uniform: non-divergent
        const float* row = p + (size_t)y * FIR_W + lane * 8;
        lo = *reinterpret_cast<const float4*>(row);
        hi = *reinterpret_cast<const float4*>(row + 4);
    } else {
        lo.x = lo.y = lo.z = lo.w = 0.0f;
        hi = lo;
    }
}

__device__ __forceinline__ F8 hfilter(float4 lo, float4 hi, int lane) {
    float xm1 = __shfl_up(hi.w, 1);    // col c-1
    float xp8 = __shfl_down(lo.x, 1);  // col c+8
    float xp9 = __shfl_down(lo.y, 1);  // col c+9
    if (lane == 0)  xm1 = 0.0f;
    if (lane == 63) { xp8 = 0.0f; xp9 = 0.0f; }
    F8 h;
    h.a.x = xm1  + 3.0f * (lo.x + lo.y) + lo.z;
    h.a.y = lo.x + 3.0f * (lo.y + lo.z) + lo.w;
    h.a.z = lo.y + 3.0f * (lo.z + lo.w) + hi.x;
    h.a.w = lo.z + 3.0f * (lo.w + hi.x) + hi.y;
    h.b.x = lo.w + 3.0f * (hi.x + hi.y) + hi.z;
    h.b.y = hi.x + 3.0f * (hi.y + hi.z) + hi.w;
    h.b.z = hi.y + 3.0f * (hi.z + hi.w) + xp8;
    h.b.w = hi.z + 3.0f * (hi.w + xp8)  + xp9;
    return h;
}

__device__ __forceinline__ float4 vcomb(float4 h0, float4 h1, float4 h2, float4 h3) {
    const float s = 1.0f / 64.0f;
    float4 o;
    o.x = (h0.x + h3.x + 3.0f * (h1.x + h2.x)) * s;
    o.y = (h0.y + h3.y + 3.0f * (h1.y + h2.y)) * s;
    o.z = (h0.z + h3.z + 3.0f * (h1.z + h2.z)) * s;
    o.w = (h0.w + h3.w + 3.0f * (h1.w + h2.w)) * s;
    return o;
}

__global__ __launch_bounds__(256) void FIRFilter_88579405512825_kernel(
        const float* __restrict__ x, float* __restrict__ out) {
    const int lane  = threadIdx.x;                               // 0..63: 8 cols each
    const int strip = blockIdx.x * blockDim.y + threadIdx.y;     // 64-row strip
    const int plane = blockIdx.y;                                // 0..511: (b, c) plane

    const float* p = x   + (size_t)plane * (FIR_W * FIR_H);
    float*       q = out + (size_t)plane * (FIR_W * FIR_H);

    const int r0 = strip * FIR_ROWS;

    // H-window entering iteration r: hm1=H(r-1), h0=H(r), hp1=H(r+1).
    F8 hm1, h0, hp1;
    {
        float4 lo, hi;
        load_row(p, r0 - 1, lane, lo, hi); hm1 = hfilter(lo, hi, lane);
        load_row(p, r0,     lane, lo, hi); h0  = hfilter(lo, hi, lane);
        load_row(p, r0 + 1, lane, lo, hi); hp1 = hfilter(lo, hi, lane);
    }

    // Pipeline prologue: raw rows r0+2, r0+3 in buffer A.
    float4 A0lo, A0hi, A1lo, A1hi;
    float4 B0lo, B0hi, B1lo, B1hi;
    load_row(p, r0 + 2, lane, A0lo, A0hi);
    load_row(p, r0 + 3, lane, A1lo, A1hi);

    for (int r = r0; r < r0 + FIR_ROWS; r += 4) {
        // ---- half 1: consume A (rows r+2, r+3); prefetch B (rows r+4, r+5) ----
        load_row(p, r + 4, lane, B0lo, B0hi);
        load_row(p, r + 5, lane, B1lo, B1hi);
        {
            F8 hp2 = hfilter(A0lo, A0hi, lane);
            F8 hp3 = hfilter(A1lo, A1hi, lane);
            float* qr = q + (size_t)r * FIR_W + lane * 8;
            *reinterpret_cast<float4*>(qr)             = vcomb(hm1.a, h0.a, hp1.a, hp2.a);
            *reinterpret_cast<float4*>(qr + 4)         = vcomb(hm1.b, h0.b, hp1.b, hp2.b);
            *reinterpret_cast<float4*>(qr + FIR_W)     = vcomb(h0.a, hp1.a, hp2.a, hp3.a);
            *reinterpret_cast<float4*>(qr + FIR_W + 4) = vcomb(h0.b, hp1.b, hp2.b, hp3.b);
            hm1 = hp1; h0 = hp2; hp1 = hp3;
        }
        // ---- half 2: consume B (rows r+4, r+5); prefetch A (rows r+6, r+7) ----
        load_row(p, r + 6, lane, A0lo, A0hi);
        load_row(p, r + 7, lane, A1lo, A1hi);
        {
            F8 hp2 = hfilter(B0lo, B0hi, lane);
            F8 hp3 = hfilter(B1lo, B1hi, lane);
            float* qr = q + (size_t)(r + 2) * FIR_W + lane * 8;
            *reinterpret_cast<float4*>(qr)             = vcomb(hm1.a, h0.a, hp1.a, hp2.a);
            *reinterpret_cast<float4*>(qr + 4)         = vcomb(hm1.b, h0.b, hp1.b, hp2.b);
            *reinterpret_cast<float4*>(qr + FIR_W)     = vcomb(h0.a, hp1.a, hp2.a, hp3.a);
            *reinterpret_cast<float4*>(qr + FIR_W + 4) = vcomb(h0.b, hp1.b, hp2.b, hp3.b);
            hm1 = hp1; h0 = hp2; hp1 = hp3;
        }
    }
}

extern "C" void kernel_launch(void* const* d_in, const int* in_sizes, int n_in,
                              void* d_out, int out_size, void* d_ws, size_t ws_size,
                              hipStream_t stream) {
    const float* x = (const float*)d_in[0];
    float* out = (float*)d_out;

    const int planes = in_sizes[0] / (FIR_W * FIR_H);   // 8*64 = 512

    // block: 64 lanes (one wave per row-strip) x 4 strips = 256 threads
    dim3 block(64, 4);
    // grid.x: 512 rows / (64 rows * 4 strips) = 2 ; grid.y: planes
    dim3 grid(FIR_H / (FIR_ROWS * 4), planes);

    FIRFilter_88579405512825_kernel<<<grid, block, 0, stream>>>(x, out);
}

// Round 6
// 305.562 us; speedup vs baseline: 1.1787x; 1.0713x over previous
//
#include <hip/hip_runtime.h>

// FIR 4x4 separable depthwise filter, k1=[1,3,3,1], k2=outer(k1,k1)/64.
// Input x: (8, 64, 512, 512) f32 -> 512 planes of 512x512.
// lax SAME padding: pad_lo=1, pad_hi=2 (zeros).
// out[r][c] = (1/64) * (H[r-1][c] + 3*H[r][c] + 3*H[r+1][c] + H[r+2][c])
//   H[y][c] = x[y][c-1] + 3*x[y][c] + 3*x[y][c+1] + x[y][c+2]
//
// One wave64 spans a full 512-wide row. KEY FIX vs R2/R5: lane i owns cols
// [4i..4i+3] (chunk A) and [256+4i..256+4i+3] (chunk B), so EVERY load and
// store instruction covers a contiguous 1 KB span -- each 128 B line is
// fully written by a single store (R5 profile: 8-contig-floats/lane layout
// gave 32 B-stride half-line stores -> WRITE_SIZE 805 MB vs 537 MB ideal).
// A/B seam (cols 255/256/257) handled by 3 wave broadcasts; image edges at
// lane 0 / lane 63. Simple rolling-window loop (R5 lesson: explicit reg
// pipeline regressed vs compiler's own schedule).

#define FIR_W 512
#define FIR_H 512
#define FIR_ROWS 64   // rows per wave-strip

struct F8 { float4 a, b; };

__device__ __forceinline__ void load_row(const float* __restrict__ p, int y, int lane,
                                         float4& A, float4& B) {
    if ((unsigned)y < FIR_H) {   // y is wave-uniform: non-divergent
        const float* row = p + (size_t)y * FIR_W;
        A = *reinterpret_cast<const float4*>(row + 4 * lane);        // cols 4i..4i+3
        B = *reinterpret_cast<const float4*>(row + 256 + 4 * lane);  // cols 256+4i..
    } else {
        A.x = A.y = A.z = A.w = 0.0f;
        B = A;
    }
}

__device__ __forceinline__ F8 hfilter(float4 A, float4 B, int lane) {
    // Seam values between chunk A (cols 0..255) and chunk B (cols 256..511):
    float c255 = __shfl(A.w, 63);  // col 255
    float c256 = __shfl(B.x, 0);   // col 256
    float c257 = __shfl(B.y, 0);   // col 257

    float a_m1 = __shfl_up(A.w, 1);    // col 4i-1
    float a_p4 = __shfl_down(A.x, 1);  // col 4i+4
    float a_p5 = __shfl_down(A.y, 1);  // col 4i+5
    if (lane == 0)  a_m1 = 0.0f;                    // image left edge (pad)
    if (lane == 63) { a_p4 = c256; a_p5 = c257; }   // seam into chunk B

    float b_m1 = __shfl_up(B.w, 1);
    float b_p4 = __shfl_down(B.x, 1);
    float b_p5 = __shfl_down(B.y, 1);
    if (lane == 0)  b_m1 = c255;                    // seam from chunk A
    if (lane == 63) { b_p4 = 0.0f; b_p5 = 0.0f; }   // image right edge (pad)

    F8 h;
    h.a.x = a_m1 + 3.0f * (A.x + A.y) + A.z;
    h.a.y = A.x  + 3.0f * (A.y + A.z) + A.w;
    h.a.z = A.y  + 3.0f * (A.z + A.w) + a_p4;
    h.a.w = A.z  + 3.0f * (A.w + a_p4) + a_p5;
    h.b.x = b_m1 + 3.0f * (B.x + B.y) + B.z;
    h.b.y = B.x  + 3.0f * (B.y + B.z) + B.w;
    h.b.z = B.y  + 3.0f * (B.z + B.w) + b_p4;
    h.b.w = B.z  + 3.0f * (B.w + b_p4) + b_p5;
    return h;
}

__device__ __forceinline__ float4 vcomb(float4 h0, float4 h1, float4 h2, float4 h3) {
    const float s = 1.0f / 64.0f;
    float4 o;
    o.x = (h0.x + h3.x + 3.0f * (h1.x + h2.x)) * s;
    o.y = (h0.y + h3.y + 3.0f * (h1.y + h2.y)) * s;
    o.z = (h0.z + h3.z + 3.0f * (h1.z + h2.z)) * s;
    o.w = (h0.w + h3.w + 3.0f * (h1.w + h2.w)) * s;
    return o;
}

__global__ __launch_bounds__(256) void FIRFilter_88579405512825_kernel(
        const float* __restrict__ x, float* __restrict__ out) {
    const int lane  = threadIdx.x;                               // 0..63
    const int strip = blockIdx.x * blockDim.y + threadIdx.y;     // 64-row strip
    const int plane = blockIdx.y;                                // 0..511: (b, c) plane

    const float* p = x   + (size_t)plane * (FIR_W * FIR_H);
    float*       q = out + (size_t)plane * (FIR_W * FIR_H);

    const int r0 = strip * FIR_ROWS;

    // Rolling window: need H(r-1..r+2) for output row r.
    F8 h1, h2, h3;
    {
        float4 A, B;
        load_row(p, r0 - 1, lane, A, B); h1 = hfilter(A, B, lane);
        load_row(p, r0,     lane, A, B); h2 = hfilter(A, B, lane);
        load_row(p, r0 + 1, lane, A, B); h3 = hfilter(A, B, lane);
    }

    #pragma unroll 4
    for (int r = r0; r < r0 + FIR_ROWS; ++r) {
        F8 h0 = h1; h1 = h2; h2 = h3;
        float4 A, B;
        load_row(p, r + 2, lane, A, B);
        h3 = hfilter(A, B, lane);

        float* qr = q + (size_t)r * FIR_W;
        *reinterpret_cast<float4*>(qr + 4 * lane)       = vcomb(h0.a, h1.a, h2.a, h3.a);
        *reinterpret_cast<float4*>(qr + 256 + 4 * lane) = vcomb(h0.b, h1.b, h2.b, h3.b);
    }
}

extern "C" void kernel_launch(void* const* d_in, const int* in_sizes, int n_in,
                              void* d_out, int out_size, void* d_ws, size_t ws_size,
                              hipStream_t stream) {
    const float* x = (const float*)d_in[0];
    float* out = (float*)d_out;

    const int planes = in_sizes[0] / (FIR_W * FIR_H);   // 8*64 = 512

    // block: 64 lanes (one wave per row-strip) x 4 strips = 256 threads
    dim3 block(64, 4);
    // grid.x: 512 rows / (64 rows * 4 strips) = 2 ; grid.y: planes
    dim3 grid(FIR_H / (FIR_ROWS * 4), planes);

    FIRFilter_88579405512825_kernel<<<grid, block, 0, stream>>>(x, out);
}

// Round 7
// 237.914 us; speedup vs baseline: 1.5139x; 1.2843x over previous
//
#include <hip/hip_runtime.h>

// FIR 4x4 separable depthwise filter, k1=[1,3,3,1], k2=outer(k1,k1)/64.
// Input x: (8, 64, 512, 512) f32 -> 512 planes of 512x512.
// lax SAME padding: pad_lo=1, pad_hi=2 (zeros).
// out[r][c] = (1/64) * (H[r-1][c] + 3*H[r][c] + 3*H[r+1][c] + H[r+2][c])
//   H[y][c] = x[y][c-1] + 3*x[y][c] + 3*x[y][c+1] + x[y][c+2]
//
// R2 structure verbatim (one wave per 512-wide row, 8 contiguous floats/lane,
// 3 halo shuffles/row -- cheapest hfilter; R6 showed ideal-contiguous stores
// with 9 shuffles/row is a net LOSS, so stores stay half-line interleaved).
// Single change vs R2: FIR_ROWS 64 -> 32, doubling workgroups to 2048 =
// 8 blocks/CU x 4 waves = 32 waves/CU (100% static occupancy, was 50%).
// Theory: latency-bound; 2x resident waves -> 2x outstanding loads per CU.

#define FIR_W 512
#define FIR_H 512
#define FIR_ROWS 32   // rows per wave-strip (was 64: only 50% occupancy ceiling)

struct F8 { float4 a, b; };

__device__ __forceinline__ F8 fir_hrow(const float* __restrict__ p, int y, int lane) {
    F8 h;
    if ((unsigned)y >= FIR_H) {   // y is wave-uniform: branch is non-divergent
        h.a.x = h.a.y = h.a.z = h.a.w = 0.0f;
        h.b = h.a;
        return h;
    }
    const float* row = p + (size_t)y * FIR_W + lane * 8;
    const float4 lo = *reinterpret_cast<const float4*>(row);      // c..c+3
    const float4 hi = *reinterpret_cast<const float4*>(row + 4);  // c+4..c+7

    float xm1 = __shfl_up(hi.w, 1);    // col c-1  (lane-1's elem 7)
    float xp8 = __shfl_down(lo.x, 1);  // col c+8  (lane+1's elem 0)
    float xp9 = __shfl_down(lo.y, 1);  // col c+9  (lane+1's elem 1)
    if (lane == 0)  xm1 = 0.0f;        // left image edge (pad_lo=1)
    if (lane == 63) { xp8 = 0.0f; xp9 = 0.0f; }  // right edge (pad_hi=2)

    h.a.x = xm1  + 3.0f * (lo.x + lo.y) + lo.z;
    h.a.y = lo.x + 3.0f * (lo.y + lo.z) + lo.w;
    h.a.z = lo.y + 3.0f * (lo.z + lo.w) + hi.x;
    h.a.w = lo.z + 3.0f * (lo.w + hi.x) + hi.y;
    h.b.x = lo.w + 3.0f * (hi.x + hi.y) + hi.z;
    h.b.y = hi.x + 3.0f * (hi.y + hi.z) + hi.w;
    h.b.z = hi.y + 3.0f * (hi.z + hi.w) + xp8;
    h.b.w = hi.z + 3.0f * (hi.w + xp8)  + xp9;
    return h;
}

__device__ __forceinline__ float4 fir_vcomb(float4 h0, float4 h1, float4 h2, float4 h3) {
    const float s = 1.0f / 64.0f;
    float4 o;
    o.x = (h0.x + h3.x + 3.0f * (h1.x + h2.x)) * s;
    o.y = (h0.y + h3.y + 3.0f * (h1.y + h2.y)) * s;
    o.z = (h0.z + h3.z + 3.0f * (h1.z + h2.z)) * s;
    o.w = (h0.w + h3.w + 3.0f * (h1.w + h2.w)) * s;
    return o;
}

__global__ __launch_bounds__(256) void FIRFilter_88579405512825_kernel(
        const float* __restrict__ x, float* __restrict__ out) {
    const int lane  = threadIdx.x;                               // 0..63: 8 cols each
    const int strip = blockIdx.x * blockDim.y + threadIdx.y;     // 32-row strip
    const int plane = blockIdx.y;                                // 0..511: (b, c) plane

    const float* p = x   + (size_t)plane * (FIR_W * FIR_H);
    float*       q = out + (size_t)plane * (FIR_W * FIR_H);

    const int r0 = strip * FIR_ROWS;

    // Rolling window of horizontal-filtered rows: need H(r-1..r+2) for row r.
    F8 h1 = fir_hrow(p, r0 - 1, lane);
    F8 h2 = fir_hrow(p, r0,     lane);
    F8 h3 = fir_hrow(p, r0 + 1, lane);

    #pragma unroll 4
    for (int r = r0; r < r0 + FIR_ROWS; ++r) {
        F8 h0 = h1; h1 = h2; h2 = h3;
        h3 = fir_hrow(p, r + 2, lane);

        float* qr = q + (size_t)r * FIR_W + lane * 8;
        *reinterpret_cast<float4*>(qr)     = fir_vcomb(h0.a, h1.a, h2.a, h3.a);
        *reinterpret_cast<float4*>(qr + 4) = fir_vcomb(h0.b, h1.b, h2.b, h3.b);
    }
}

extern "C" void kernel_launch(void* const* d_in, const int* in_sizes, int n_in,
                              void* d_out, int out_size, void* d_ws, size_t ws_size,
                              hipStream_t stream) {
    const float* x = (const float*)d_in[0];
    float* out = (float*)d_out;

    const int planes = in_sizes[0] / (FIR_W * FIR_H);   // 8*64 = 512

    // block: 64 lanes (one wave per row-strip) x 4 strips = 256 threads
    dim3 block(64, 4);
    // grid.x: 512 rows / (32 rows * 4 strips) = 4 ; grid.y: planes
    dim3 grid(FIR_H / (FIR_ROWS * 4), planes);

    FIRFilter_88579405512825_kernel<<<grid, block, 0, stream>>>(x, out);
}

// Round 8
// 223.777 us; speedup vs baseline: 1.6095x; 1.0632x over previous
//
#include <hip/hip_runtime.h>

// FIR 4x4 separable depthwise filter, k1=[1,3,3,1], k2=outer(k1,k1)/64.
// Input x: (8, 64, 512, 512) f32 -> 512 planes of 512x512.
// lax SAME padding: pad_lo=1, pad_hi=2 (zeros).
// out[r][c] = (1/64) * (H[r-1][c] + 3*H[r][c] + 3*H[r+1][c] + H[r+2][c])
//   H[y][c] = x[y][c-1] + 3*x[y][c] + 3*x[y][c+1] + x[y][c+2]
//
// R8: 4 floats/lane. One wave owns a 256-col half-row, so EVERY load and
// store is one dwordx4 covering a fully contiguous 1 KB span -> zero write
// amplification (R5 profile: 8-floats/lane gave 32 B-stride half-line
// stores, WRITE_SIZE 805 MB vs 537 MB ideal). hfilter stays at 3 shuffles
// per row (R6 lesson: 9 shuffles/row cost more than coalescing saved).
// Half-row seam (cols 255..257) via ONE predicated dwordx4 load active in
// a single lane (L1/L2 hit). FIR_ROWS=32: 32 waves/CU available.

#define FIR_W 512
#define FIR_H 512
#define FIR_ROWS 32   // rows per wave-strip

__device__ __forceinline__ float4 fir_hrow(const float* __restrict__ p, int y,
                                           int lane, int c0) {
    float4 h;
    if ((unsigned)y >= FIR_H) {   // y is wave-uniform: non-divergent
        h.x = h.y = h.z = h.w = 0.0f;
        return h;
    }
    const float* row = p + (size_t)y * FIR_W;
    const float4 v = *reinterpret_cast<const float4*>(row + c0 + 4 * lane);

    // Seam values from the other half-row (or zeros at image edges):
    // lane 0 (right panel) needs cols c0-4..c0-1; lane 63 (left panel)
    // needs cols c0+256..259. One predicated gather, <=1 active lane.
    float4 s; s.x = s.y = s.z = s.w = 0.0f;
    if (lane == 0 && c0 != 0)
        s = *reinterpret_cast<const float4*>(row + c0 - 4);
    if (lane == 63 && c0 == 0)
        s = *reinterpret_cast<const float4*>(row + c0 + 256);

    float xm1 = __shfl_up(v.w, 1);     // col c-1
    float xp4 = __shfl_down(v.x, 1);   // col c+4
    float xp5 = __shfl_down(v.y, 1);   // col c+5
    if (lane == 0)  xm1 = s.w;                 // seam or zero-pad (s=0 at c0==0)
    if (lane == 63) { xp4 = s.x; xp5 = s.y; }  // seam or zero-pad (s=0 at c0==256)

    h.x = xm1 + 3.0f * (v.x + v.y) + v.z;
    h.y = v.x + 3.0f * (v.y + v.z) + v.w;
    h.z = v.y + 3.0f * (v.z + v.w) + xp4;
    h.w = v.z + 3.0f * (v.w + xp4) + xp5;
    return h;
}

__device__ __forceinline__ float4 fir_vcomb(float4 h0, float4 h1, float4 h2, float4 h3) {
    const float s = 1.0f / 64.0f;
    float4 o;
    o.x = (h0.x + h3.x + 3.0f * (h1.x + h2.x)) * s;
    o.y = (h0.y + h3.y + 3.0f * (h1.y + h2.y)) * s;
    o.z = (h0.z + h3.z + 3.0f * (h1.z + h2.z)) * s;
    o.w = (h0.w + h3.w + 3.0f * (h1.w + h2.w)) * s;
    return o;
}

__global__ __launch_bounds__(256) void FIRFilter_88579405512825_kernel(
        const float* __restrict__ x, float* __restrict__ out) {
    const int lane = threadIdx.x;                             // 0..63: 4 cols each
    const int w    = blockIdx.x * blockDim.y + threadIdx.y;   // 0..31: wave task
    const int half  = w & 1;                                  // half-row panel
    const int strip = w >> 1;                                 // 32-row strip
    const int plane = blockIdx.y;                             // 0..511: (b,c) plane
    const int c0 = half * 256;

    const float* p = x   + (size_t)plane * (FIR_W * FIR_H);
    float*       q = out + (size_t)plane * (FIR_W * FIR_H);

    const int r0 = strip * FIR_ROWS;

    // Rolling window: need H(r-1..r+2) for output row r.
    float4 h1 = fir_hrow(p, r0 - 1, lane, c0);
    float4 h2 = fir_hrow(p, r0,     lane, c0);
    float4 h3 = fir_hrow(p, r0 + 1, lane, c0);

    #pragma unroll 4
    for (int r = r0; r < r0 + FIR_ROWS; ++r) {
        float4 h0 = h1; h1 = h2; h2 = h3;
        h3 = fir_hrow(p, r + 2, lane, c0);

        *reinterpret_cast<float4*>(q + (size_t)r * FIR_W + c0 + 4 * lane)
            = fir_vcomb(h0, h1, h2, h3);
    }
}

extern "C" void kernel_launch(void* const* d_in, const int* in_sizes, int n_in,
                              void* d_out, int out_size, void* d_ws, size_t ws_size,
                              hipStream_t stream) {
    const float* x = (const float*)d_in[0];
    float* out = (float*)d_out;

    const int planes = in_sizes[0] / (FIR_W * FIR_H);   // 8*64 = 512

    // block: 64 lanes x 4 waves = 256 threads; 32 wave-tasks per plane
    // (2 half-row panels x 16 strips of 32 rows) -> grid.x = 8.
    dim3 block(64, 4);
    dim3 grid(8, planes);

    FIRFilter_88579405512825_kernel<<<grid, block, 0, stream>>>(x, out);
}

// Round 9
// 222.664 us; speedup vs baseline: 1.6175x; 1.0050x over previous
//
#include <hip/hip_runtime.h>

// FIR 4x4 separable depthwise filter, k1=[1,3,3,1], k2=outer(k1,k1)/64.
// Input x: (8, 64, 512, 512) f32 -> 512 planes of 512x512.
// lax SAME padding: pad_lo=1, pad_hi=2 (zeros).
// out[r][c] = (1/64) * (H[r-1][c] + 3*H[r][c] + 3*H[r+1][c] + H[r+2][c])
//   H[y][c] = x[y][c-1] + 3*x[y][c] + 3*x[y][c+1] + x[y][c+2]
//
// R9: R8 layout (4 floats/lane; one wave owns a 256-col half-row; every
// load/store = one dwordx4 over a contiguous 1 KB span; 3 shuffles/row)
// x TWO INDEPENDENT PLANES per wave. Five prior variants with traffic
// 0.96-1.40 GB all measured 224-238 us -> limiter is not BW, not occupancy,
// not store coalescing, not instruction count. Remaining axis: per-wave
// memory-level parallelism (every prior wave ran ONE dependent
// load->shuffle->compute->store chain). Two independent streams double
// outstanding loads per wave and batch VMEM 2-at-a-time.
// __launch_bounds__(256,4): cap 128 VGPR (16 waves/CU suffices -- R2 ran
// at ~41% occupancy and matched 100%-occupancy R7).

#define FIR_W 512
#define FIR_H 512
#define FIR_ROWS 32   // rows per wave-strip
#define PLANE_SZ ((size_t)FIR_W * FIR_H)

__device__ __forceinline__ float4 fir_hfilt(float4 v, float4 s, int lane) {
    float xm1 = __shfl_up(v.w, 1);     // col c-1
    float xp4 = __shfl_down(v.x, 1);   // col c+4
    float xp5 = __shfl_down(v.y, 1);   // col c+5
    if (lane == 0)  xm1 = s.w;                 // seam or zero-pad
    if (lane == 63) { xp4 = s.x; xp5 = s.y; }  // seam or zero-pad
    float4 h;
    h.x = xm1 + 3.0f * (v.x + v.y) + v.z;
    h.y = v.x + 3.0f * (v.y + v.z) + v.w;
    h.z = v.y + 3.0f * (v.z + v.w) + xp4;
    h.w = v.z + 3.0f * (v.w + xp4) + xp5;
    return h;
}

// Load row y of both planes (and seam fragments), then filter both.
// Both main loads issue before any dependent shuffle -> 2 loads in flight.
__device__ __forceinline__ void fir_hrow2(const float* __restrict__ pA,
                                          const float* __restrict__ pB,
                                          int y, int lane, int c0,
                                          float4& hA, float4& hB) {
    if ((unsigned)y >= FIR_H) {   // wave-uniform
        hA.x = hA.y = hA.z = hA.w = 0.0f;
        hB = hA;
        return;
    }
    const size_t rowoff = (size_t)y * FIR_W;
    const float* rowA = pA + rowoff;
    const float* rowB = pB + rowoff;
    const float4 vA = *reinterpret_cast<const float4*>(rowA + c0 + 4 * lane);
    const float4 vB = *reinterpret_cast<const float4*>(rowB + c0 + 4 * lane);

    // Seam values from the other half-row (<=1 active lane per plane).
    float4 sA, sB;
    sA.x = sA.y = sA.z = sA.w = 0.0f;
    sB = sA;
    if (lane == 0 && c0 != 0) {
        sA = *reinterpret_cast<const float4*>(rowA + c0 - 4);
        sB = *reinterpret_cast<const float4*>(rowB + c0 - 4);
    }
    if (lane == 63 && c0 == 0) {
        sA = *reinterpret_cast<const float4*>(rowA + 256);
        sB = *reinterpret_cast<const float4*>(rowB + 256);
    }

    hA = fir_hfilt(vA, sA, lane);
    hB = fir_hfilt(vB, sB, lane);
}

__device__ __forceinline__ float4 fir_vcomb(float4 h0, float4 h1, float4 h2, float4 h3) {
    const float s = 1.0f / 64.0f;
    float4 o;
    o.x = (h0.x + h3.x + 3.0f * (h1.x + h2.x)) * s;
    o.y = (h0.y + h3.y + 3.0f * (h1.y + h2.y)) * s;
    o.z = (h0.z + h3.z + 3.0f * (h1.z + h2.z)) * s;
    o.w = (h0.w + h3.w + 3.0f * (h1.w + h2.w)) * s;
    return o;
}

__global__ __launch_bounds__(256, 4) void FIRFilter_88579405512825_kernel(
        const float* __restrict__ x, float* __restrict__ out) {
    const int lane = threadIdx.x;                             // 0..63: 4 cols each
    const int w    = blockIdx.x * blockDim.y + threadIdx.y;   // 0..31: wave task
    const int half  = w & 1;                                  // half-row panel
    const int strip = w >> 1;                                 // 32-row strip
    const int pp    = blockIdx.y;                             // 0..255: plane pair
    const int c0 = half * 256;

    const float* pA = x + (size_t)(2 * pp) * PLANE_SZ;
    const float* pB = pA + PLANE_SZ;
    float* qA = out + (size_t)(2 * pp) * PLANE_SZ;
    float* qB = qA + PLANE_SZ;

    const int r0 = strip * FIR_ROWS;

    // Rolling windows (per plane): need H(r-1..r+2) for output row r.
    float4 a1, a2, a3, b1, b2, b3;
    fir_hrow2(pA, pB, r0 - 1, lane, c0, a1, b1);
    fir_hrow2(pA, pB, r0,     lane, c0, a2, b2);
    fir_hrow2(pA, pB, r0 + 1, lane, c0, a3, b3);

    #pragma unroll 4
    for (int r = r0; r < r0 + FIR_ROWS; ++r) {
        float4 a0 = a1; a1 = a2; a2 = a3;
        float4 b0 = b1; b1 = b2; b2 = b3;
        fir_hrow2(pA, pB, r + 2, lane, c0, a3, b3);

        const size_t off = (size_t)r * FIR_W + c0 + 4 * lane;
        *reinterpret_cast<float4*>(qA + off) = fir_vcomb(a0, a1, a2, a3);
        *reinterpret_cast<float4*>(qB + off) = fir_vcomb(b0, b1, b2, b3);
    }
}

extern "C" void kernel_launch(void* const* d_in, const int* in_sizes, int n_in,
                              void* d_out, int out_size, void* d_ws, size_t ws_size,
                              hipStream_t stream) {
    const float* x = (const float*)d_in[0];
    float* out = (float*)d_out;

    const int planes = in_sizes[0] / (FIR_W * FIR_H);   // 8*64 = 512

    // block: 64 lanes x 4 waves = 256 threads; 32 wave-tasks per plane-pair
    // (2 half-row panels x 16 strips of 32 rows) -> grid.x = 8.
    dim3 block(64, 4);
    dim3 grid(8, planes / 2);

    FIRFilter_88579405512825_kernel<<<grid, block, 0, stream>>>(x, out);
}

// Round 10
// 214.653 us; speedup vs baseline: 1.6779x; 1.0373x over previous
//
#include <hip/hip_runtime.h>

// FIR 4x4 separable depthwise filter, k1=[1,3,3,1], k2=outer(k1,k1)/64.
// Input x: (8, 64, 512, 512) f32 -> 512 planes of 512x512.
// lax SAME padding: pad_lo=1, pad_hi=2 (zeros).
// out[r][c] = (1/64) * (H[r-1][c] + 3*H[r][c] + 3*H[r+1][c] + H[r+2][c])
//   H[y][c] = x[y][c-1] + 3*x[y][c] + 3*x[y][c+1] + x[y][c+2]
//
// R10 = R9 (4 floats/lane, 256-col half-row per wave, every load/store one
// dwordx4 over a contiguous 1 KB span = 8 FULLY-COVERED 128 B lines per
// wave-store; 3 shuffles/row; 2 independent planes/wave) + NONTEMPORAL
// stores. R4's NT failure (WRITE 2x) was caused by the then-current
// half-line store pattern (16 B @ 32 B stride) -> partial-line RMW when L2
// merging was bypassed. With full-line stores, NT should stream full 128 B
// bursts AND stop write-allocating 537 MB in L3, which currently evicts
// the input stream (FETCH 286-393 MB = input only ~40% L3-resident).
// Discriminating observable: WRITE_SIZE must stay ~524288 KB.

#define FIR_W 512
#define FIR_H 512
#define FIR_ROWS 32   // rows per wave-strip
#define PLANE_SZ ((size_t)FIR_W * FIR_H)

typedef float fvec4 __attribute__((ext_vector_type(4)));  // native vec for nt-store

__device__ __forceinline__ void nt_store4(float* addr, float4 v) {
    fvec4 n = {v.x, v.y, v.z, v.w};
    __builtin_nontemporal_store(n, reinterpret_cast<fvec4*>(addr));
}

__device__ __forceinline__ float4 fir_hfilt(float4 v, float4 s, int lane) {
    float xm1 = __shfl_up(v.w, 1);     // col c-1
    float xp4 = __shfl_down(v.x, 1);   // col c+4
    float xp5 = __shfl_down(v.y, 1);   // col c+5
    if (lane == 0)  xm1 = s.w;                 // seam or zero-pad
    if (lane == 63) { xp4 = s.x; xp5 = s.y; }  // seam or zero-pad
    float4 h;
    h.x = xm1 + 3.0f * (v.x + v.y) + v.z;
    h.y = v.x + 3.0f * (v.y + v.z) + v.w;
    h.z = v.y + 3.0f * (v.z + v.w) + xp4;
    h.w = v.z + 3.0f * (v.w + xp4) + xp5;
    return h;
}

// Load row y of both planes (and seam fragments), then filter both.
__device__ __forceinline__ void fir_hrow2(const float* __restrict__ pA,
                                          const float* __restrict__ pB,
                                          int y, int lane, int c0,
                                          float4& hA, float4& hB) {
    if ((unsigned)y >= FIR_H) {   // wave-uniform
        hA.x = hA.y = hA.z = hA.w = 0.0f;
        hB = hA;
        return;
    }
    const size_t rowoff = (size_t)y * FIR_W;
    const float* rowA = pA + rowoff;
    const float* rowB = pB + rowoff;
    const float4 vA = *reinterpret_cast<const float4*>(rowA + c0 + 4 * lane);
    const float4 vB = *reinterpret_cast<const float4*>(rowB + c0 + 4 * lane);

    // Seam values from the other half-row (<=1 active lane per plane).
    float4 sA, sB;
    sA.x = sA.y = sA.z = sA.w = 0.0f;
    sB = sA;
    if (lane == 0 && c0 != 0) {
        sA = *reinterpret_cast<const float4*>(rowA + c0 - 4);
        sB = *reinterpret_cast<const float4*>(rowB + c0 - 4);
    }
    if (lane == 63 && c0 == 0) {
        sA = *reinterpret_cast<const float4*>(rowA + 256);
        sB = *reinterpret_cast<const float4*>(rowB + 256);
    }

    hA = fir_hfilt(vA, sA, lane);
    hB = fir_hfilt(vB, sB, lane);
}

__device__ __forceinline__ float4 fir_vcomb(float4 h0, float4 h1, float4 h2, float4 h3) {
    const float s = 1.0f / 64.0f;
    float4 o;
    o.x = (h0.x + h3.x + 3.0f * (h1.x + h2.x)) * s;
    o.y = (h0.y + h3.y + 3.0f * (h1.y + h2.y)) * s;
    o.z = (h0.z + h3.z + 3.0f * (h1.z + h2.z)) * s;
    o.w = (h0.w + h3.w + 3.0f * (h1.w + h2.w)) * s;
    return o;
}

__global__ __launch_bounds__(256, 4) void FIRFilter_88579405512825_kernel(
        const float* __restrict__ x, float* __restrict__ out) {
    const int lane = threadIdx.x;                             // 0..63: 4 cols each
    const int w    = blockIdx.x * blockDim.y + threadIdx.y;   // 0..31: wave task
    const int half  = w & 1;                                  // half-row panel
    const int strip = w >> 1;                                 // 32-row strip
    const int pp    = blockIdx.y;                             // 0..255: plane pair
    const int c0 = half * 256;

    const float* pA = x + (size_t)(2 * pp) * PLANE_SZ;
    const float* pB = pA + PLANE_SZ;
    float* qA = out + (size_t)(2 * pp) * PLANE_SZ;
    float* qB = qA + PLANE_SZ;

    const int r0 = strip * FIR_ROWS;

    // Rolling windows (per plane): need H(r-1..r+2) for output row r.
    float4 a1, a2, a3, b1, b2, b3;
    fir_hrow2(pA, pB, r0 - 1, lane, c0, a1, b1);
    fir_hrow2(pA, pB, r0,     lane, c0, a2, b2);
    fir_hrow2(pA, pB, r0 + 1, lane, c0, a3, b3);

    #pragma unroll 4
    for (int r = r0; r < r0 + FIR_ROWS; ++r) {
        float4 a0 = a1; a1 = a2; a2 = a3;
        float4 b0 = b1; b1 = b2; b2 = b3;
        fir_hrow2(pA, pB, r + 2, lane, c0, a3, b3);

        const size_t off = (size_t)r * FIR_W + c0 + 4 * lane;
        nt_store4(qA + off, fir_vcomb(a0, a1, a2, a3));
        nt_store4(qB + off, fir_vcomb(b0, b1, b2, b3));
    }
}

extern "C" void kernel_launch(void* const* d_in, const int* in_sizes, int n_in,
                              void* d_out, int out_size, void* d_ws, size_t ws_size,
                              hipStream_t stream) {
    const float* x = (const float*)d_in[0];
    float* out = (float*)d_out;

    const int planes = in_sizes[0] / (FIR_W * FIR_H);   // 8*64 = 512

    // block: 64 lanes x 4 waves = 256 threads; 32 wave-tasks per plane-pair
    // (2 half-row panels x 16 strips of 32 rows) -> grid.x = 8.
    dim3 block(64, 4);
    dim3 grid(8, planes / 2);

    FIRFilter_88579405512825_kernel<<<grid, block, 0, stream>>>(x, out);
}